// Round 9
// baseline (160.773 us; speedup 1.0000x reference)
//
#include <hip/hip_runtime.h>

#define NN 62      // nodes per graph
#define NP 64      // padded row stride
#define NBATCH 1024
#define IN_CH 5
#define HID 64
#define OUT_CH 3
#define NTRIL 1953
#define GTS 68     // sGT float stride: /4=17 (odd) -> b128 reads conflict-free

// ---------------------------------------------------------------------------
// setup: 64 blocks x 64 threads. Block n<62 emits A2 row n (cols>=62 zero);
// blocks 62,63 emit zero rows (so main kernel needs no K-guards). All blocks
// also emit W2T row n (w2 transposed) for wave-uniform dwordx8 access.
// ---------------------------------------------------------------------------
__global__ __launch_bounds__(64) void setup_k(const float* __restrict__ p,
                                              const float* __restrict__ w2,
                                              float* __restrict__ A2g,
                                              float* __restrict__ W2Tg) {
    __shared__ float sA[NN * NP];
    __shared__ float sDinv[NN];
    const int lane = threadIdx.x;
    const int n = blockIdx.x;           // 0..63

    W2Tg[n * NP + lane] = w2[lane * HID + n];   // W2T[m][j] = w2[j][m]

    for (int i = lane; i < NN * NP; i += 64) sA[i] = 0.f;
    __syncthreads();

    for (int i = lane; i < NTRIL; i += 64) {
        int r = (int)((sqrtf(8.f * (float)i + 1.f) - 1.f) * 0.5f);
        while (r * (r + 1) / 2 > i) --r;
        while ((r + 1) * (r + 2) / 2 <= i) ++r;
        int c = i - r * (r + 1) / 2;
        float v = p[i];
        sA[r * NP + c] = v;
        sA[c * NP + r] = v;
    }
    __syncthreads();

    if (lane < NN) {
        float s = 0.f;
        for (int j = 0; j < NN; ++j) s += fabsf(sA[lane * NP + j]);
        sDinv[lane] = (s > 0.f) ? (1.0f / sqrtf(s)) : 0.f;
    }
    __syncthreads();

    for (int i = lane; i < NN * NP; i += 64) {
        int r = i >> 6, c = i & 63;
        float dc = (c < NN) ? sDinv[c] : 0.f;
        sA[i] = sDinv[r] * sA[i] * dc;   // pad cols stay 0
    }
    __syncthreads();

    float acc = 0.f;
    if (n < NN)
        for (int k = 0; k < NN; ++k) acc += sA[n * NP + k] * sA[k * NP + lane];
    A2g[n * NP + lane] = acc;            // rows/cols >= 62 are exactly 0
}

// ---------------------------------------------------------------------------
// main: 1024 blocks x 512 threads = 8 waves/graph, strips of 8.
// R8 post-mortem: 4096 waves = 4 waves/SIMD couldn't hide the s_load chains
// (occupancy 27.7%). Same dataflow, halved per-wave strips -> 8192 waves =
// 8 waves/SIMD of latency hiding.
//  Y1: lane=node; A2 columns coalesced from global (symmetric), X broadcast
//      via v_readlane from registers (zero LDS).
//  H1->G fused: h(m) regenerated per m (8x redundant, ~35% of VALU — the
//      price of TLP); G[8] accumulators; W2T row slice via s_load_dwordx8.
//  hop-2: G column via 4 conflict-free b128 per k-block; A2 16-wide blocks
//      via wave-uniform s_loads (K$).
// All private arrays strictly compile-time indexed (R4/R7: spill traps).
// launch_bounds (512,6): 85-VGPR budget — estimate ~50 live, margin vs R7.
// ---------------------------------------------------------------------------
__global__ __launch_bounds__(512, 6) void graph_net(
    const float* __restrict__ x_, const float* __restrict__ A2g_,
    const float* __restrict__ w1_, const float* __restrict__ b1_,
    const float* __restrict__ w2t_, const float* __restrict__ b2_,
    const float* __restrict__ wfc, const float* __restrict__ bfc,
    float* __restrict__ out) {
    __shared__ float sGT[HID * GTS];     // 17408 B: G transposed [chan][node]
    __shared__ float sPool[8 * NP];      // 2048 B
    // total 19456 B -> LDS allows 8 blocks/CU; grid gives 4

    const float* x   = (const float*)__builtin_assume_aligned(x_, 16);
    const float* A2g = (const float*)__builtin_assume_aligned(A2g_, 16);
    const float* w1  = (const float*)__builtin_assume_aligned(w1_, 16);
    const float* b1  = (const float*)__builtin_assume_aligned(b1_, 16);
    const float* w2t = (const float*)__builtin_assume_aligned(w2t_, 16);
    const float* b2  = (const float*)__builtin_assume_aligned(b2_, 16);

    const int t = threadIdx.x;
    const int lane = t & 63;
    const int w = __builtin_amdgcn_readfirstlane(t >> 6);  // wave id 0..7
    const int g = blockIdx.x;
    const float* xg = x + (size_t)g * (NN * IN_CH);

    // ---- X into registers: lane L holds x[g][L][0..4] (clamp lanes 62/63)
    int xi[IN_CH];
    {
        const int L = (lane < NN) ? lane : (NN - 1);
        const int* xgi = (const int*)xg;
#pragma unroll
        for (int c = 0; c < IN_CH; ++c) xi[c] = xgi[L * IN_CH + c];
    }

    // ---- Y1[lane][c] = sum_k A2[k][lane] * X[k][c]
    //      A2 read as columns (symmetric) -> coalesced dword loads;
    //      X[k][c] via v_readlane (no LDS). Lanes 62/63: A2 cols are 0 -> y1=0.
    float y1[IN_CH] = {0.f, 0.f, 0.f, 0.f, 0.f};
#pragma unroll 4
    for (int k = 0; k < NN; ++k) {
        float a2k = A2g[k * NP + lane];   // coalesced 256B/wave, L1-hot
        float x0 = __int_as_float(__builtin_amdgcn_readlane(xi[0], k));
        float x1 = __int_as_float(__builtin_amdgcn_readlane(xi[1], k));
        float x2 = __int_as_float(__builtin_amdgcn_readlane(xi[2], k));
        float x3 = __int_as_float(__builtin_amdgcn_readlane(xi[3], k));
        float x4 = __int_as_float(__builtin_amdgcn_readlane(xi[4], k));
        y1[0] += a2k * x0; y1[1] += a2k * x1; y1[2] += a2k * x2;
        y1[3] += a2k * x3; y1[4] += a2k * x4;
    }

    // ---- H1 -> G fused: G[n][j] = sum_m relu(b1[m] + y1·W1[m]) * W2T[m][j]
    //      for this wave's 8-channel slice j in [jBase, jBase+8)
    float G[8];
#pragma unroll
    for (int i = 0; i < 8; ++i) G[i] = 0.f;
    const int jBase = w * 8;
#pragma unroll 4
    for (int m = 0; m < HID; ++m) {
        const float* wr = w1 + m * IN_CH;       // K$-hot (1.3 KB)
        float h = b1[m];
        h += y1[0] * wr[0]; h += y1[1] * wr[1]; h += y1[2] * wr[2];
        h += y1[3] * wr[3]; h += y1[4] * wr[4];
        h = fmaxf(h, 0.f);
        const float* wt = w2t + m * NP + jBase; // wave-uniform dwordx8
#pragma unroll
        for (int jj = 0; jj < 8; ++jj) G[jj] += h * wt[jj];
    }
    // store transposed: sGT[chan j][node lane]
    if (lane < NN) {
#pragma unroll
        for (int jj = 0; jj < 8; ++jj) sGT[(jBase + jj) * GTS + lane] = G[jj];
    }
    // zero node-cols 62/63 of all 64 channel rows
    if (t < 128) sGT[(t >> 1) * GTS + NN + (t & 1)] = 0.f;
    __syncthreads();

    // ---- hop-2 + relu + pool: lane = channel, wave strips 8 nodes.
    //      k in 4 blocks of 16: G block via 4 b128 (stride-17-float4 ->
    //      conflict-free), A2[n][kblock] via wave-uniform s_loads (K$).
    const int nBase = w * 8;
    float H2[8];
#pragma unroll
    for (int i = 0; i < 8; ++i) H2[i] = 0.f;
#pragma unroll
    for (int kb = 0; kb < 4; ++kb) {
        const float* gt = sGT + lane * GTS + kb * 16;
        float4 g0 = *(const float4*)(gt + 0);
        float4 g1 = *(const float4*)(gt + 4);
        float4 g2 = *(const float4*)(gt + 8);
        float4 g3 = *(const float4*)(gt + 12);
#pragma unroll
        for (int ni = 0; ni < 8; ++ni) {
            const float* a2s = A2g + (nBase + ni) * NP + kb * 16;  // s_load x16
            float p0 = a2s[0] * g0.x + a2s[1] * g0.y + a2s[2] * g0.z + a2s[3] * g0.w;
            float p1 = a2s[4] * g1.x + a2s[5] * g1.y + a2s[6] * g1.z + a2s[7] * g1.w;
            float p2 = a2s[8] * g2.x + a2s[9] * g2.y + a2s[10] * g2.z + a2s[11] * g2.w;
            float p3 = a2s[12] * g3.x + a2s[13] * g3.y + a2s[14] * g3.z + a2s[15] * g3.w;
            H2[ni] += (p0 + p1) + (p2 + p3);
        }
    }
    const float b2r = b2[lane];
    float pooled = 0.f;
#pragma unroll
    for (int ni = 0; ni < 8; ++ni) {
        if (nBase + ni < NN)                     // wave-uniform guard
            pooled += fmaxf(b2r + H2[ni], 0.f);
    }
    sPool[w * NP + lane] = pooled;
    __syncthreads();

    // ---- reduce pool over 8 waves, then fc (3 outputs)
    if (w == 0) {
        float ph = sPool[lane];
#pragma unroll
        for (int q = 1; q < 8; ++q) ph += sPool[q * NP + lane];
        sPool[lane] = ph;
    }
    __syncthreads();
    if (t < OUT_CH) {
        float v = bfc[t];
        const float* wr = wfc + t * HID;
        for (int h = 0; h < HID; ++h) v += sPool[h] * wr[h];
        out[g * OUT_CH + t] = v;
    }
}

// ---------------------------------------------------------------------------
extern "C" void kernel_launch(void* const* d_in, const int* in_sizes, int n_in,
                              void* d_out, int out_size, void* d_ws, size_t ws_size,
                              hipStream_t stream) {
    const float* x   = (const float*)d_in[0];
    // d_in[1] = edge_index, d_in[2] = batch: fixed/deterministic -> unused
    const float* ewp = (const float*)d_in[3];
    const float* w1  = (const float*)d_in[4];
    const float* b1  = (const float*)d_in[5];
    const float* w2  = (const float*)d_in[6];
    const float* b2  = (const float*)d_in[7];
    const float* wfc = (const float*)d_in[8];
    const float* bfc = (const float*)d_in[9];
    float* out = (float*)d_out;

    float* A2g  = (float*)d_ws;            // 64*64 floats
    float* W2Tg = A2g + NP * NP;           // 64*64 floats

    setup_k<<<NP, 64, 0, stream>>>(ewp, w2, A2g, W2Tg);
    graph_net<<<NBATCH, 512, 0, stream>>>(x, A2g, w1, b1, W2Tg, b2, wfc, bfc, out);
}

// Round 10
// 127.010 us; speedup vs baseline: 1.2658x; 1.2658x over previous
//
#include <hip/hip_runtime.h>

#define NN 62      // nodes per graph
#define NP 64      // padded row/col stride
#define NBATCH 1024
#define IN_CH 5
#define HID 64
#define OUT_CH 3
#define NTRIL 1953
#define H1S 72     // sH1 f16 stride: 144 B = 9*16 -> b128-aligned rows, 2-way banks
#define GS 17      // sG f32 stride: <=2-way banks for both D-store and B-read

typedef _Float16 f16;
typedef f16 half8 __attribute__((ext_vector_type(8)));
typedef float floatx4 __attribute__((ext_vector_type(4)));

// ---------------------------------------------------------------------------
// setup: 64 blocks x 64 threads. Block n emits A2 row n (fp32 + f16 hi/lo
// split; rows/cols >= 62 exactly zero) and W2 row n split (w2h/w2l, [j][m]
// layout = B-operand k-contiguous).
// ---------------------------------------------------------------------------
__global__ __launch_bounds__(64) void setup_k(const float* __restrict__ p,
                                              const float* __restrict__ w2,
                                              float* __restrict__ A2g,
                                              f16* __restrict__ a2h,
                                              f16* __restrict__ a2l,
                                              f16* __restrict__ w2h,
                                              f16* __restrict__ w2l) {
    __shared__ float sA[NN * NP];
    __shared__ float sDinv[NN];
    const int lane = threadIdx.x;
    const int n = blockIdx.x;           // 0..63

    // W2 split (exact: wl = fl(w - fl16(w)))
    {
        float wv = w2[n * HID + lane];
        f16 wh = (f16)wv;
        w2h[n * NP + lane] = wh;
        w2l[n * NP + lane] = (f16)(wv - (float)wh);
    }

    for (int i = lane; i < NN * NP; i += 64) sA[i] = 0.f;
    __syncthreads();

    for (int i = lane; i < NTRIL; i += 64) {
        int r = (int)((sqrtf(8.f * (float)i + 1.f) - 1.f) * 0.5f);
        while (r * (r + 1) / 2 > i) --r;
        while ((r + 1) * (r + 2) / 2 <= i) ++r;
        int c = i - r * (r + 1) / 2;
        float v = p[i];
        sA[r * NP + c] = v;
        sA[c * NP + r] = v;
    }
    __syncthreads();

    if (lane < NN) {
        float s = 0.f;
        for (int j = 0; j < NN; ++j) s += fabsf(sA[lane * NP + j]);
        sDinv[lane] = (s > 0.f) ? (1.0f / sqrtf(s)) : 0.f;
    }
    __syncthreads();

    for (int i = lane; i < NN * NP; i += 64) {
        int r = i >> 6, c = i & 63;
        float dc = (c < NN) ? sDinv[c] : 0.f;
        sA[i] = sDinv[r] * sA[i] * dc;   // pad cols stay 0
    }
    __syncthreads();

    float acc = 0.f;
    if (n < NN)
        for (int k = 0; k < NN; ++k) acc += sA[n * NP + k] * sA[k * NP + lane];
    A2g[n * NP + lane] = acc;            // rows/cols >= 62 exactly 0
    f16 ah = (f16)acc;
    a2h[n * NP + lane] = ah;
    a2l[n * NP + lane] = (f16)(acc - (float)ah);
}

// ---------------------------------------------------------------------------
// main: 1024 blocks x 256 threads (4 waves/graph; wave w owns 16-column strip
// j in [16w,16w+16)).
//  Stage1 (fp32 VALU, exact): Y1 = A2@X (thread (n,q) k-split + shfl), then
//    H1 = relu(Y1@W1^T) with lane=m, split-converted to f16 hi/lo in LDS.
//  G = H1 @ W2T via 3-term split-f16 MFMA (A=H1 from LDS b128, B=W2 rows
//    from setup-split global, batch-invariant).
//  G D-frags -> per-wave LDS -> re-split as B-frags (intra-wave turn).
//  H2 = A2 @ G via 3-term split-f16 MFMA (A=A2 hi/lo from global, L1-hot).
//  Epilogue: relu(b2+H2), mask rows>=62, pool via shfl, fc.
// Empirical law from R5-R9: ~3us per M wave-instructions -> this kernel's
// ~0.7k VALU + 48 MFMA per wave is ~4x leaner than R5.
// ---------------------------------------------------------------------------
__global__ __launch_bounds__(256, 4) void graph_net(
    const float* __restrict__ x, const float* __restrict__ A2g,
    const f16* __restrict__ a2h, const f16* __restrict__ a2l,
    const f16* __restrict__ w2h, const f16* __restrict__ w2l,
    const float* __restrict__ w1, const float* __restrict__ b1,
    const float* __restrict__ b2,
    const float* __restrict__ wfc, const float* __restrict__ bfc,
    float* __restrict__ out) {
    __shared__ float sY1[NP * 8];        // 2 KB
    __shared__ f16 sH1h[NP * H1S];       // 9216 B
    __shared__ f16 sH1l[NP * H1S];       // 9216 B
    __shared__ float sG[4 * NP * GS];    // 17408 B (per-wave 64x17 regions)
    __shared__ float sPool[NP];          // 256 B

    const int t = threadIdx.x;
    const int lane = t & 63;
    const int w = __builtin_amdgcn_readfirstlane(t >> 6);
    const int g = blockIdx.x;
    const float* xg = x + (size_t)g * (NN * IN_CH);

    // ---- Y1: thread (n = t>>2, q = t&3) sums k ≡ q (mod 4); shfl-combine
    {
        const int n = t >> 2;
        const int q = t & 3;
        float y0 = 0.f, y1v = 0.f, y2 = 0.f, y3 = 0.f, y4 = 0.f;
        if (n < NN) {
#pragma unroll
            for (int j = 0; j < 16; ++j) {
                int k = q + 4 * j;
                if (k < NN) {
                    float a = A2g[n * NP + k];      // L1-hot 16 KB
                    const float* xr = xg + k * IN_CH;
                    y0 += a * xr[0]; y1v += a * xr[1]; y2 += a * xr[2];
                    y3 += a * xr[3]; y4 += a * xr[4];
                }
            }
        }
        y0 += __shfl_xor(y0, 1); y0 += __shfl_xor(y0, 2);
        y1v += __shfl_xor(y1v, 1); y1v += __shfl_xor(y1v, 2);
        y2 += __shfl_xor(y2, 1); y2 += __shfl_xor(y2, 2);
        y3 += __shfl_xor(y3, 1); y3 += __shfl_xor(y3, 2);
        y4 += __shfl_xor(y4, 1); y4 += __shfl_xor(y4, 2);
        if (q == 0 && n < NN) {
            float4 v; v.x = y0; v.y = y1v; v.z = y2; v.w = y3;
            *(float4*)(sY1 + n * 8) = v;
            sY1[n * 8 + 4] = y4;
        }
    }
    __syncthreads();

    // ---- H1: wave w handles node rows 16w..16w+15 (skip >=62); lane = m
    {
        const float* wr = w1 + lane * IN_CH;
        float q0 = wr[0], q1 = wr[1], q2 = wr[2], q3 = wr[3], q4 = wr[4];
        float bb = b1[lane];
#pragma unroll
        for (int ni = 0; ni < 16; ++ni) {
            const int n = 16 * w + ni;
            if (n < NN) {
                float4 yv = *(const float4*)(sY1 + n * 8);
                float y4v = sY1[n * 8 + 4];
                float h = bb + yv.x * q0 + yv.y * q1 + yv.z * q2
                             + yv.w * q3 + y4v * q4;
                h = fmaxf(h, 0.f);
                f16 hh = (f16)h;
                sH1h[n * H1S + lane] = hh;
                sH1l[n * H1S + lane] = (f16)(h - (float)hh);
            }
        }
    }
    // zero H1 rows 62,63 (uninit LDS could be NaN-patterned; 0*W2 must be 0)
    if (t < 128) {
        const int n = 62 + (t >> 6);
        sH1h[n * H1S + (t & 63)] = (f16)0.f;
        sH1l[n * H1S + (t & 63)] = (f16)0.f;
    }
    __syncthreads();

    const int jn = lane & 15;            // column within strip / A-row in tile
    const int qd = lane >> 4;            // quad
    const int jglob = 16 * w + jn;

    // ---- G = H1 @ W2T, 3-term split-f16 MFMA. B = W2 rows (k=m contiguous).
    half8 bWh[2], bWl[2];
#pragma unroll
    for (int ks = 0; ks < 2; ++ks) {
        bWh[ks] = *(const half8*)(w2h + jglob * NP + qd * 8 + 32 * ks);
        bWl[ks] = *(const half8*)(w2l + jglob * NP + qd * 8 + 32 * ks);
    }
    floatx4 Cg[4];
#pragma unroll
    for (int T = 0; T < 4; ++T) { Cg[T][0]=0.f; Cg[T][1]=0.f; Cg[T][2]=0.f; Cg[T][3]=0.f; }
#pragma unroll
    for (int T = 0; T < 4; ++T) {
#pragma unroll
        for (int ks = 0; ks < 2; ++ks) {
            const half8 aH = *(const half8*)(sH1h + (16 * T + jn) * H1S + qd * 8 + 32 * ks);
            const half8 aL = *(const half8*)(sH1l + (16 * T + jn) * H1S + qd * 8 + 32 * ks);
            Cg[T] = __builtin_amdgcn_mfma_f32_16x16x32_f16(aL, bWh[ks], Cg[T], 0, 0, 0);
            Cg[T] = __builtin_amdgcn_mfma_f32_16x16x32_f16(aH, bWl[ks], Cg[T], 0, 0, 0);
            Cg[T] = __builtin_amdgcn_mfma_f32_16x16x32_f16(aH, bWh[ks], Cg[T], 0, 0, 0);
        }
    }
    // ---- D-layout G -> per-wave LDS (row k = 16T+qd*4+r, col jn)
    {
        float* gw = sG + w * (NP * GS);
#pragma unroll
        for (int T = 0; T < 4; ++T)
#pragma unroll
            for (int r = 0; r < 4; ++r)
                gw[(16 * T + qd * 4 + r) * GS + jn] = Cg[T][r];
    }
    __syncthreads();   // order LDS writes before re-reads (also inter-wave safe)

    // ---- rebuild G as B-frags (k = qd*8+i+32ks, col jn) with fresh hi/lo split
    half8 bGh[2], bGl[2];
    {
        const float* gw = sG + w * (NP * GS);
#pragma unroll
        for (int ks = 0; ks < 2; ++ks) {
#pragma unroll
            for (int i = 0; i < 8; ++i) {
                float v = gw[(qd * 8 + i + 32 * ks) * GS + jn];
                f16 vh = (f16)v;
                bGh[ks][i] = vh;
                bGl[ks][i] = (f16)(v - (float)vh);
            }
        }
    }

    // ---- H2 = A2 @ G, 3-term split-f16 MFMA. A = A2 hi/lo (global, L1-hot).
    floatx4 C2[4];
#pragma unroll
    for (int T = 0; T < 4; ++T) { C2[T][0]=0.f; C2[T][1]=0.f; C2[T][2]=0.f; C2[T][3]=0.f; }
#pragma unroll
    for (int T = 0; T < 4; ++T) {
#pragma unroll
        for (int ks = 0; ks < 2; ++ks) {
            const half8 aH = *(const half8*)(a2h + (16 * T + jn) * NP + qd * 8 + 32 * ks);
            const half8 aL = *(const half8*)(a2l + (16 * T + jn) * NP + qd * 8 + 32 * ks);
            C2[T] = __builtin_amdgcn_mfma_f32_16x16x32_f16(aL, bGh[ks], C2[T], 0, 0, 0);
            C2[T] = __builtin_amdgcn_mfma_f32_16x16x32_f16(aH, bGl[ks], C2[T], 0, 0, 0);
            C2[T] = __builtin_amdgcn_mfma_f32_16x16x32_f16(aH, bGh[ks], C2[T], 0, 0, 0);
        }
    }

    // ---- epilogue: relu(b2+H2), mask n>=62, pool over n, fc
    {
        const float b2r = b2[jglob];
        float pool = 0.f;
#pragma unroll
        for (int T = 0; T < 4; ++T) {
#pragma unroll
            for (int r = 0; r < 4; ++r) {
                int n = 16 * T + qd * 4 + r;
                float v = fmaxf(C2[T][r] + b2r, 0.f);
                pool += (n < NN) ? v : 0.f;
            }
        }
        pool += __shfl_xor(pool, 16);
        pool += __shfl_xor(pool, 32);
        if (lane < 16) sPool[16 * w + lane] = pool;
    }
    __syncthreads();

    if (t < OUT_CH) {
        float v = bfc[t];
        const float* wr = wfc + t * HID;
#pragma unroll
        for (int h = 0; h < HID; ++h) v += sPool[h] * wr[h];
        out[g * OUT_CH + t] = v;
    }
}

// ---------------------------------------------------------------------------
extern "C" void kernel_launch(void* const* d_in, const int* in_sizes, int n_in,
                              void* d_out, int out_size, void* d_ws, size_t ws_size,
                              hipStream_t stream) {
    const float* x   = (const float*)d_in[0];
    // d_in[1] = edge_index, d_in[2] = batch: fixed/deterministic -> unused
    const float* ewp = (const float*)d_in[3];
    const float* w1  = (const float*)d_in[4];
    const float* b1  = (const float*)d_in[5];
    const float* w2  = (const float*)d_in[6];
    const float* b2  = (const float*)d_in[7];
    const float* wfc = (const float*)d_in[8];
    const float* bfc = (const float*)d_in[9];
    float* out = (float*)d_out;

    float* A2g = (float*)d_ws;                 // 64*64 f32
    f16* a2h = (f16*)(A2g + NP * NP);          // 64*64 f16 each
    f16* a2l = a2h + NP * NP;
    f16* w2h = a2l + NP * NP;
    f16* w2l = w2h + NP * NP;

    setup_k<<<NP, 64, 0, stream>>>(ewp, w2, A2g, a2h, a2l, w2h, w2l);
    graph_net<<<NBATCH, 256, 0, stream>>>(x, A2g, a2h, a2l, w2h, w2l,
                                          w1, b1, b2, wfc, bfc, out);
}